// Round 3
// baseline (13188.776 us; speedup 1.0000x reference)
//
#include <hip/hip_runtime.h>

// Decoder: 2-layer LSTM, B=1024, IN=256, H=512, OUT=256, T2=128 (hardcoded).
// PERSISTENT kernel, 256 blocks x 512 thr. 16 batch-groups (64 rows) x 16
// j-tiles (32 h-cols). Coherence protocol (the round-2 fix):
//   - shared-mutable data (h, z, out) written with agent-scope (sc1) atomic
//     stores -> write-through to L3. NO plain dirty lines exist in L2.
//   - consumers use PLAIN cached loads; a single acquire-fence (buffer_inv,
//     invalidates L1+L2) per block per barrier makes them fresh, and same-XCD
//     blocks then SHARE panels/weights through L2 (16x redundancy removed).
//   - one lock-step 2-level global barrier so all invalidates cluster and the
//     phase runs on a warm L2. Weights pre-swizzled to MFMA B-frag order,
//     j-pinned via blockIdx&7 for XCD L2 affinity. c-state lives in VGPRs.

typedef __attribute__((ext_vector_type(8))) __bf16 bf16x8;
typedef __attribute__((ext_vector_type(16))) float f32x16;
typedef unsigned long long ull;

__device__ __forceinline__ f32x16 mfma_bf16(bf16x8 a, bf16x8 b, f32x16 c) {
  return __builtin_amdgcn_mfma_f32_32x32x16_bf16(a, b, c, 0, 0, 0);
}

__device__ __forceinline__ short f2bf(float f) {  // RNE fp32->bf16
  unsigned u = __float_as_uint(f);
  u += 0x7fffu + ((u >> 16) & 1u);
  return (short)(u >> 16);
}

__device__ __forceinline__ float sigm(float x) { return 1.0f / (1.0f + __expf(-x)); }
__device__ __forceinline__ float tanh_fast(float x) { return 2.0f / (1.0f + __expf(-2.0f * x)) - 1.0f; }

__device__ __forceinline__ f32x16 zero16() {
  f32x16 z;
#pragma unroll
  for (int i = 0; i < 16; ++i) z[i] = 0.0f;
  return z;
}

// A-tile LDS layout: row m (0..63) at stride 132 shorts (16 k8-slots * 8 + 4
// pad). Frag reads: 264B row stride -> 2-way bank alias (free, m136).
// Staging ds_write_b128: banks (m*33 + ks*4)%32 all-distinct -> conflict-free.
#define AT_STRIDE 132
#define AT_WORDS (64 * AT_STRIDE)  // 8448 shorts = 16896 B per tile

// ---------------------------------------------------------------------------
// prep: swizzle weights into per-(block, k16-step, gate) lane-contiguous MFMA
// B-fragments; sum biases; init bf16 states; zero barrier flags.
// ---------------------------------------------------------------------------
__global__ __launch_bounds__(256) void prep_kernel(
    const float* __restrict__ z0, const float* __restrict__ h0in,
    const float* __restrict__ Wih0, const float* __restrict__ Whh0,
    const float* __restrict__ bih0, const float* __restrict__ bhh0,
    const float* __restrict__ Wih1, const float* __restrict__ Whh1,
    const float* __restrict__ bih1, const float* __restrict__ bhh1,
    const float* __restrict__ fcW, const float* __restrict__ linW,
    short* __restrict__ wsw0, short* __restrict__ wsw1,
    short* __restrict__ fcWsw, short* __restrict__ linWsw,
    float* __restrict__ bias0, float* __restrict__ bias1,
    short* __restrict__ zb1, short* __restrict__ h0b0, short* __restrict__ h1b0,
    int* __restrict__ flags)
{
  int idx = blockIdx.x * 256 + threadIdx.x;
  if (idx < 1572864) {  // wsw0 [b16][s48][g4][l64][j8]; K=768 = [z 256 | h0 512]
    int jj = idx & 7, l = (idx >> 3) & 63, gg = (idx >> 9) & 3;
    int rest = idx >> 11;           // b*48 + s
    int s = rest % 48, b = rest / 48;
    int row = gg * 512 + b * 32 + (l & 31);
    int k = s * 16 + (l >> 5) * 8 + jj;
    wsw0[idx] = f2bf(k < 256 ? Wih0[row * 256 + k] : Whh0[row * 512 + (k - 256)]);
    return;
  }
  idx -= 1572864;
  if (idx < 2097152) {  // wsw1 [b16][s64][g4][l64][j8]; K=1024 = [h0 512 | h1 512]
    int jj = idx & 7, l = (idx >> 3) & 63, gg = (idx >> 9) & 3;
    int rest = idx >> 11;           // b*64 + s
    int s = rest & 63, b = rest >> 6;
    int row = gg * 512 + b * 32 + (l & 31);
    int k = s * 16 + (l >> 5) * 8 + jj;
    wsw1[idx] = f2bf(k < 512 ? Wih1[row * 512 + k] : Whh1[row * 512 + (k - 512)]);
    return;
  }
  idx -= 2097152;
  if (idx < 131072) {  // fcWsw [jz8][s32][l64][j8]; N-slice 32, K=512
    int jj = idx & 7, l = (idx >> 3) & 63, s = (idx >> 9) & 31, jz = idx >> 14;
    int col = jz * 32 + (l & 31);
    int k = s * 16 + (l >> 5) * 8 + jj;
    fcWsw[idx] = f2bf(fcW[col * 512 + k]);
    return;
  }
  idx -= 131072;
  if (idx < 65536) {  // linWsw [jo8][s16][l64][j8]; N-slice 32, K=256
    int jj = idx & 7, l = (idx >> 3) & 63, s = (idx >> 9) & 15, jo = idx >> 13;
    int col = jo * 32 + (l & 31);
    int k = s * 16 + (l >> 5) * 8 + jj;
    linWsw[idx] = f2bf(linW[col * 256 + k]);
    return;
  }
  idx -= 65536;
  if (idx < 2048) { bias0[idx] = bih0[idx] + bhh0[idx]; return; }
  idx -= 2048;
  if (idx < 2048) { bias1[idx] = bih1[idx] + bhh1[idx]; return; }
  idx -= 2048;
  if (idx < 262144) { zb1[idx] = f2bf(z0[idx]); return; }
  idx -= 262144;
  if (idx < 524288) { h0b0[idx] = f2bf(h0in[idx]); return; }
  idx -= 524288;
  if (idx < 524288) { h1b0[idx] = f2bf(h0in[524288 + idx]); return; }
  idx -= 524288;
  if (idx < 12288) { flags[idx] = 0; return; }
}

// ---------------------------------------------------------------------------
// 2-level lock-step global barrier (all 256 blocks). Per phase: 16 group
// flags + 1 super flag (flags + pc*32: [0..15] group, [16] super).
// Acquire fence (buffer_inv) AFTER the barrier => plain loads see all sc1
// stores; same-XCD blocks then share refetched lines via L2.
// ---------------------------------------------------------------------------
__device__ __forceinline__ void global_barrier(int* base, int g, bool leader) {
  __syncthreads();   // drains each wave's vmcnt => sc1 stores visible at L3
  if (threadIdx.x == 0) {
    int* gf = base + g;
    int* sf = base + 16;
    __hip_atomic_fetch_add(gf, 1, __ATOMIC_RELAXED, __HIP_MEMORY_SCOPE_AGENT);
    if (leader) {
      while (__hip_atomic_load(gf, __ATOMIC_RELAXED, __HIP_MEMORY_SCOPE_AGENT) < 16)
        __builtin_amdgcn_s_sleep(1);
      __hip_atomic_fetch_add(sf, 1, __ATOMIC_RELAXED, __HIP_MEMORY_SCOPE_AGENT);
    }
    while (__hip_atomic_load(sf, __ATOMIC_RELAXED, __HIP_MEMORY_SCOPE_AGENT) < 16)
      __builtin_amdgcn_s_sleep(1);
    __builtin_amdgcn_fence(__ATOMIC_ACQUIRE, "agent");  // buffer_inv: L1+L2
  }
  __syncthreads();
}

// ---------------------------------------------------------------------------
// LSTM cell phase: gates = [A|B panels] @ Wblk^T + bias; c in regs; h -> sc1.
// Waves: (gate = w>>1, m-half = w&1). K128 tiles, double-buffered LDS,
// PLAIN cached panel loads (4 x 256B segments per wave-instruction).
// ---------------------------------------------------------------------------
template <int NT, int TA>
__device__ __forceinline__ void cell_phase(
    short* At0, short* At1, float* gbuf,
    const short* __restrict__ srcA, int ldA,
    const short* __restrict__ srcB, int ldB,
    const short* __restrict__ wblk, const float* __restrict__ bias,
    float* cr, ull* hout, int row0, int j0)
{
  const int t = threadIdx.x;
  const int w = t >> 6, l = t & 63;
  const int gq = w >> 1, mh = w & 1;
  const int ln = l & 31, kh = l >> 5;
  const int sks = t & 15, sm = t >> 4;   // staging: ks 0..15, m 0..31 (+32)
  short* Abuf[2] = {At0, At1};
  f32x16 acc = zero16();
  uint4 pre[2];
#pragma unroll
  for (int i = 0; i < 2; ++i)
    pre[i] = *(const uint4*)&srcA[(row0 + sm + 32 * i) * ldA + sks * 8];
#pragma unroll
  for (int i = 0; i < 2; ++i)
    *(uint4*)&Abuf[0][(sm + 32 * i) * AT_STRIDE + sks * 8] = pre[i];
  __syncthreads();
#pragma unroll
  for (int tau = 0; tau < NT; ++tau) {
    if (tau + 1 < NT) {
      const short* src; int ld, col;
      if (tau + 1 < TA) { src = srcA; ld = ldA; col = (tau + 1) * 128; }
      else              { src = srcB; ld = ldB; col = (tau + 1 - TA) * 128; }
#pragma unroll
      for (int i = 0; i < 2; ++i)
        pre[i] = *(const uint4*)&src[(row0 + sm + 32 * i) * ld + col + sks * 8];
    }
    const short* at = Abuf[tau & 1];
#pragma unroll
    for (int s = 0; s < 8; ++s) {
      bf16x8 a = *(const bf16x8*)&at[(mh * 32 + ln) * AT_STRIDE + (s * 2 + kh) * 8];
      bf16x8 b = *(const bf16x8*)&wblk[(((tau * 8 + s) * 4 + gq) * 64 + l) * 8];
      acc = mfma_bf16(a, b, acc);
    }
    if (tau + 1 < NT) {
      short* nxt = Abuf[(tau + 1) & 1];
#pragma unroll
      for (int i = 0; i < 2; ++i)
        *(uint4*)&nxt[(sm + 32 * i) * AT_STRIDE + sks * 8] = pre[i];
    }
    __syncthreads();
  }
  // C layout: col = lane&31, row = (r&3)+8*(r>>2)+4*(lane>>5). gbuf aliases
  // the A tiles (all MFMA LDS reads drained by the loop's final sync).
#pragma unroll
  for (int r = 0; r < 16; ++r) {
    int mloc = (r & 3) + 8 * (r >> 2) + 4 * kh + mh * 32;
    gbuf[(gq * 64 + mloc) * 32 + ln] = acc[r];
  }
  __syncthreads();
  const int m = t >> 3, nb = (t & 7) * 4;
  short hh[4];
#pragma unroll
  for (int u = 0; u < 4; ++u) {
    int n = nb + u, jn = j0 + n;
    float gi = gbuf[(0 * 64 + m) * 32 + n] + bias[jn];
    float gf = gbuf[(1 * 64 + m) * 32 + n] + bias[512 + jn];
    float gg = gbuf[(2 * 64 + m) * 32 + n] + bias[1024 + jn];
    float go = gbuf[(3 * 64 + m) * 32 + n] + bias[1536 + jn];
    float cn = sigm(gf) * cr[u] + sigm(gi) * tanh_fast(gg);
    cr[u] = cn;
    hh[u] = f2bf(sigm(go) * tanh_fast(cn));
  }
  ull hv; __builtin_memcpy(&hv, hh, 8);
  __hip_atomic_store(&hout[((size_t)(row0 + m) * 512 + j0 + nb) >> 2], hv,
                     __ATOMIC_RELAXED, __HIP_MEMORY_SCOPE_AGENT);
}

// ---------------------------------------------------------------------------
// Projection partials (fc or lin): waves (kq = w>>1, mh = w&1) accumulate K32
// slices per K128 chunk; 4 K-partials land in gbuf[kq][m][n] for combine.
// ---------------------------------------------------------------------------
template <int NQ>
__device__ __forceinline__ void proj_partials(
    short* At0, float* gbuf,
    const short* __restrict__ src, int ld,
    const short* __restrict__ wblk, int row0)
{
  const int t = threadIdx.x;
  const int w = t >> 6, l = t & 63;
  const int kq = w >> 1, mh = w & 1;
  const int ln = l & 31, kh = l >> 5;
  const int sks = t & 15, sm = t >> 4;
  f32x16 acc = zero16();
#pragma unroll
  for (int q = 0; q < NQ; ++q) {
    __syncthreads();
    uint4 pre[2];
#pragma unroll
    for (int i = 0; i < 2; ++i)
      pre[i] = *(const uint4*)&src[(row0 + sm + 32 * i) * ld + q * 128 + sks * 8];
#pragma unroll
    for (int i = 0; i < 2; ++i)
      *(uint4*)&At0[(sm + 32 * i) * AT_STRIDE + sks * 8] = pre[i];
    __syncthreads();
#pragma unroll
    for (int sl = 0; sl < 2; ++sl) {
      int s16 = kq * 2 + sl;
      bf16x8 a = *(const bf16x8*)&At0[(mh * 32 + ln) * AT_STRIDE + (s16 * 2 + kh) * 8];
      bf16x8 b = *(const bf16x8*)&wblk[((q * 8 + s16) * 64 + l) * 8];
      acc = mfma_bf16(a, b, acc);
    }
  }
  __syncthreads();
#pragma unroll
  for (int r = 0; r < 16; ++r) {
    int mloc = (r & 3) + 8 * (r >> 2) + 4 * kh + mh * 32;
    gbuf[(kq * 64 + mloc) * 32 + ln] = acc[r];
  }
  __syncthreads();
}

__global__ __launch_bounds__(512, 1) void decoder_persist(
    const short* __restrict__ wsw0, const short* __restrict__ wsw1,
    const short* __restrict__ fcWsw, const short* __restrict__ linWsw,
    const float* __restrict__ bias0, const float* __restrict__ bias1,
    const float* __restrict__ fcb, const float* __restrict__ linb,
    const float* __restrict__ c0in,
    short* h0x, short* h0y, short* h1x, short* h1y, short* zx, short* zy,
    int* flags, float* __restrict__ outp)
{
  __shared__ __align__(16) char arena[2 * 2 * AT_WORDS];  // 33792 B
  short* At0 = (short*)arena;
  short* At1 = At0 + AT_WORDS;
  float* gbuf = (float*)arena;   // 32768 B, aliases the A tiles

  const int x = blockIdx.x;
  const int xcd = x & 7, rr = x >> 3;
  const int g = rr & 15, jhi = rr >> 4;
  const int j = jhi * 8 + xcd;        // j-tile: same j -> same XCD (L2 affinity)
  const int row0 = g * 64, j0 = j * 32;
  const bool leader = (j == g);       // one leader per group, spread over XCDs
  const short* wblk0 = wsw0 + j * 98304;
  const short* wblk1 = wsw1 + j * 131072;
  short* h0buf[2] = {h0x, h0y};
  short* h1buf[2] = {h1x, h1y};
  short* zbuf[2] = {zx, zy};

  // c-state in registers for the whole run
  float c0r[4], c1r[4];
  {
    const int m = threadIdx.x >> 3, nb = (threadIdx.x & 7) * 4;
#pragma unroll
    for (int u = 0; u < 4; ++u) {
      c0r[u] = c0in[(size_t)(row0 + m) * 512 + j0 + nb + u];
      c1r[u] = c0in[524288 + (size_t)(row0 + m) * 512 + j0 + nb + u];
    }
  }

  int pc = 0;
#pragma unroll 1
  for (int t = 0; t < 128; ++t) {
    const int p = t & 1;
    // P1: cell0  (K = [z 256 | h0 512])
    cell_phase<6, 2>(At0, At1, gbuf, zbuf[p ^ 1], 256, h0buf[p], 512,
                     wblk0, bias0, c0r, (ull*)h0buf[p ^ 1], row0, j0);
    global_barrier(flags + pc * 32, g, leader); ++pc;
    // P2: cell1  (K = [h0_new 512 | h1 512])
    cell_phase<8, 4>(At0, At1, gbuf, h0buf[p ^ 1], 512, h1buf[p], 512,
                     wblk1, bias1, c1r, (ull*)h1buf[p ^ 1], row0, j0);
    global_barrier(flags + pc * 32, g, leader); ++pc;
    // M3: blocks j<8 -> z(t) = fc(h1); j>=8 -> out(t-1) = lin(z(t-1))
    if (j < 8) {
      proj_partials<4>(At0, gbuf, h0buf[0] /*unused*/ , 512, fcWsw, row0);  // placeholder avoided below
    }
    if (j < 8) {
      // (recompute properly: the call above is never taken — see real call)
    }
    if (j < 8) {
      proj_partials<4>(At0, gbuf, h1buf[p ^ 1], 512, fcWsw + j * 16384, row0);
      const int m = threadIdx.x >> 3, nb = (threadIdx.x & 7) * 4;
      const int n0 = j * 32;
      short zz[4];
#pragma unroll
      for (int u = 0; u < 4; ++u) {
        int n = nb + u;
        float v = gbuf[(0 * 64 + m) * 32 + n] + gbuf[(1 * 64 + m) * 32 + n] +
                  gbuf[(2 * 64 + m) * 32 + n] + gbuf[(3 * 64 + m) * 32 + n] +
                  fcb[n0 + n];
        zz[u] = f2bf(v);
      }
      ull zv; __builtin_memcpy(&zv, zz, 8);
      __hip_atomic_store((ull*)&zbuf[p][(size_t)(row0 + m) * 256 + n0 + nb], zv,
                         __ATOMIC_RELAXED, __HIP_MEMORY_SCOPE_AGENT);
    } else if (t > 0) {
      proj_partials<2>(At0, gbuf, zbuf[p ^ 1], 256, linWsw + (j - 8) * 8192, row0);
      const int m = threadIdx.x >> 3, nb = (threadIdx.x & 7) * 4;
      const int n0 = (j - 8) * 32;
      float po[4];
#pragma unroll
      for (int u = 0; u < 4; ++u) {
        int n = nb + u;
        po[u] = gbuf[(0 * 64 + m) * 32 + n] + gbuf[(1 * 64 + m) * 32 + n] +
                gbuf[(2 * 64 + m) * 32 + n] + gbuf[(3 * 64 + m) * 32 + n] +
                linb[n0 + n];
      }
      ull v0, v1;
      __builtin_memcpy(&v0, &po[0], 8); __builtin_memcpy(&v1, &po[2], 8);
      ull* op = (ull*)&outp[(size_t)(t - 1) * 262144 + (size_t)(row0 + m) * 256 + n0 + nb];
      __hip_atomic_store(op, v0, __ATOMIC_RELAXED, __HIP_MEMORY_SCOPE_AGENT);
      __hip_atomic_store(op + 1, v1, __ATOMIC_RELAXED, __HIP_MEMORY_SCOPE_AGENT);
    }
    global_barrier(flags + pc * 32, g, leader); ++pc;
  }
  // final out(127) from z(127) in zbuf[1]
  if (j >= 8) {
    proj_partials<2>(At0, gbuf, zbuf[1], 256, linWsw + (j - 8) * 8192, row0);
    const int m = threadIdx.x >> 3, nb = (threadIdx.x & 7) * 4;
    const int n0 = (j - 8) * 32;
    float po[4];
#pragma unroll
    for (int u = 0; u < 4; ++u) {
      int n = nb + u;
      po[u] = gbuf[(0 * 64 + m) * 32 + n] + gbuf[(1 * 64 + m) * 32 + n] +
              gbuf[(2 * 64 + m) * 32 + n] + gbuf[(3 * 64 + m) * 32 + n] +
              linb[n0 + n];
    }
    ull v0, v1;
    __builtin_memcpy(&v0, &po[0], 8); __builtin_memcpy(&v1, &po[2], 8);
    ull* op = (ull*)&outp[(size_t)127 * 262144 + (size_t)(row0 + m) * 256 + n0 + nb];
    __hip_atomic_store(op, v0, __ATOMIC_RELAXED, __HIP_MEMORY_SCOPE_AGENT);
    __hip_atomic_store(op + 1, v1, __ATOMIC_RELAXED, __HIP_MEMORY_SCOPE_AGENT);
  }
}

// ---------------------------------------------------------------------------
extern "C" void kernel_launch(void* const* d_in, const int* in_sizes, int n_in,
                              void* d_out, int out_size, void* d_ws, size_t ws_size,
                              hipStream_t stream) {
  const float* z0   = (const float*)d_in[0];
  const float* h0in = (const float*)d_in[1];
  const float* c0in = (const float*)d_in[2];
  const float* Wih0 = (const float*)d_in[3];
  const float* Whh0 = (const float*)d_in[4];
  const float* bih0 = (const float*)d_in[5];
  const float* bhh0 = (const float*)d_in[6];
  const float* Wih1 = (const float*)d_in[7];
  const float* Whh1 = (const float*)d_in[8];
  const float* bih1 = (const float*)d_in[9];
  const float* bhh1 = (const float*)d_in[10];
  const float* fcW  = (const float*)d_in[11];
  const float* fcb  = (const float*)d_in[12];
  const float* linW = (const float*)d_in[13];
  const float* linb = (const float*)d_in[14];
  float* out = (float*)d_out;

  char* ws = (char*)d_ws;
  short* wsw0  = (short*)(ws + 0);         // 3,145,728 B
  short* wsw1  = (short*)(ws + 3145728);   // 4,194,304 B
  short* fcWsw = (short*)(ws + 7340032);   //   262,144 B
  short* linWsw= (short*)(ws + 7602176);   //   131,072 B
  float* bias0 = (float*)(ws + 7733248);   //     8,192 B
  float* bias1 = (float*)(ws + 7741440);   //     8,192 B
  short* zb0   = (short*)(ws + 7749632);   //   524,288 B
  short* zb1   = (short*)(ws + 8273920);   //   524,288 B
  short* h0b0  = (short*)(ws + 8798208);   // 1,048,576 B
  short* h0b1  = (short*)(ws + 9846784);
  short* h1b0  = (short*)(ws + 10895360);
  short* h1b1  = (short*)(ws + 11943936);
  int*   flags = (int*)  (ws + 12992512);  //    49,152 B  (total 13,041,664)

  prep_kernel<<<20288, 256, 0, stream>>>(z0, h0in, Wih0, Whh0, bih0, bhh0,
                                         Wih1, Whh1, bih1, bhh1, fcW, linW,
                                         wsw0, wsw1, fcWsw, linWsw, bias0, bias1,
                                         zb1, h0b0, h1b0, flags);

  decoder_persist<<<256, 512, 0, stream>>>(
      wsw0, wsw1, fcWsw, linWsw, bias0, bias1, fcb, linb, c0in,
      h0b0, h0b1, h1b0, h1b1, zb0, zb1, flags, out);
}

// Round 4
// 7997.993 us; speedup vs baseline: 1.6490x; 1.6490x over previous
//
#include <hip/hip_runtime.h>

// Decoder: 2-layer LSTM, B=1024, IN=256, H=512, OUT=256, T2=128 (hardcoded).
// PERSISTENT kernel, 256 blocks x 512 thr, 1 block/CU (forced via 148KB LDS).
// Round-4 structure: each batch-group (64 rows, 16 j-blocks) is XCD-LOCAL.
//   - blocks read HW_REG_XCC_ID and self-assign (group, j) via per-XCD atomic
//     counters => correctness never depends on blockIdx->XCD mapping.
//   - activations (h0, h1, z) exchanged through the XCD's own L2: plain
//     write-back stores + plain cached loads; freshness via per-CU buffer_inv
//     (L1-only, L2 untouched) at each 16-block group barrier.
//   - weights pre-swizzled to MFMA B-frag order; each block parks fc/lin
//     slice + 2-3 cell1 B-tiles in LDS permanently; rest streams from L2.
//   - c-state in VGPRs. Barriers: per-group monotone counter, agent atomics.

typedef __attribute__((ext_vector_type(8))) __bf16 bf16x8;
typedef __attribute__((ext_vector_type(16))) float f32x16;
typedef unsigned long long ull;

__device__ __forceinline__ f32x16 mfma_bf16(bf16x8 a, bf16x8 b, f32x16 c) {
  return __builtin_amdgcn_mfma_f32_32x32x16_bf16(a, b, c, 0, 0, 0);
}

__device__ __forceinline__ short f2bf(float f) {  // RNE fp32->bf16
  unsigned u = __float_as_uint(f);
  u += 0x7fffu + ((u >> 16) & 1u);
  return (short)(u >> 16);
}

__device__ __forceinline__ float sigm(float x) { return 1.0f / (1.0f + __expf(-x)); }
__device__ __forceinline__ float tanh_fast(float x) { return 2.0f / (1.0f + __expf(-2.0f * x)) - 1.0f; }

__device__ __forceinline__ f32x16 zero16() {
  f32x16 z;
#pragma unroll
  for (int i = 0; i < 16; ++i) z[i] = 0.0f;
  return z;
}

// A-tile LDS layout: row m (0..63) at stride 132 shorts.
#define AT_STRIDE 132
#define AT_WORDS (64 * AT_STRIDE)  // 8448 shorts = 16896 B per tile

// ---------------------------------------------------------------------------
// prep: swizzle weights into per-(j, k16-step, gate) lane-contiguous MFMA
// B-fragments; sum biases; init bf16 states; zero barrier flags + XCD ctrs.
// ---------------------------------------------------------------------------
__global__ __launch_bounds__(256) void prep_kernel(
    const float* __restrict__ z0, const float* __restrict__ h0in,
    const float* __restrict__ Wih0, const float* __restrict__ Whh0,
    const float* __restrict__ bih0, const float* __restrict__ bhh0,
    const float* __restrict__ Wih1, const float* __restrict__ Whh1,
    const float* __restrict__ bih1, const float* __restrict__ bhh1,
    const float* __restrict__ fcW, const float* __restrict__ linW,
    short* __restrict__ wsw0, short* __restrict__ wsw1,
    short* __restrict__ fcWsw, short* __restrict__ linWsw,
    float* __restrict__ bias0, float* __restrict__ bias1,
    short* __restrict__ zb1, short* __restrict__ h0b0, short* __restrict__ h1b0,
    int* __restrict__ flags)
{
  int idx = blockIdx.x * 256 + threadIdx.x;
  if (idx < 1572864) {  // wsw0 [j16][s48][g4][l64][8]; K=768 = [z 256 | h0 512]
    int jj = idx & 7, l = (idx >> 3) & 63, gg = (idx >> 9) & 3;
    int rest = idx >> 11;           // j*48 + s
    int s = rest % 48, b = rest / 48;
    int row = gg * 512 + b * 32 + (l & 31);
    int k = s * 16 + (l >> 5) * 8 + jj;
    wsw0[idx] = f2bf(k < 256 ? Wih0[row * 256 + k] : Whh0[row * 512 + (k - 256)]);
    return;
  }
  idx -= 1572864;
  if (idx < 2097152) {  // wsw1 [j16][s64][g4][l64][8]; K=1024 = [h0 512 | h1 512]
    int jj = idx & 7, l = (idx >> 3) & 63, gg = (idx >> 9) & 3;
    int rest = idx >> 11;           // j*64 + s
    int s = rest & 63, b = rest >> 6;
    int row = gg * 512 + b * 32 + (l & 31);
    int k = s * 16 + (l >> 5) * 8 + jj;
    wsw1[idx] = f2bf(k < 512 ? Wih1[row * 512 + k] : Whh1[row * 512 + (k - 512)]);
    return;
  }
  idx -= 2097152;
  if (idx < 131072) {  // fcWsw [jz8][s32][l64][8]
    int jj = idx & 7, l = (idx >> 3) & 63, s = (idx >> 9) & 31, jz = idx >> 14;
    int col = jz * 32 + (l & 31);
    int k = s * 16 + (l >> 5) * 8 + jj;
    fcWsw[idx] = f2bf(fcW[col * 512 + k]);
    return;
  }
  idx -= 131072;
  if (idx < 65536) {  // linWsw [jo8][s16][l64][8]
    int jj = idx & 7, l = (idx >> 3) & 63, s = (idx >> 9) & 15, jo = idx >> 13;
    int col = jo * 32 + (l & 31);
    int k = s * 16 + (l >> 5) * 8 + jj;
    linWsw[idx] = f2bf(linW[col * 256 + k]);
    return;
  }
  idx -= 65536;
  if (idx < 2048) { bias0[idx] = bih0[idx] + bhh0[idx]; return; }
  idx -= 2048;
  if (idx < 2048) { bias1[idx] = bih1[idx] + bhh1[idx]; return; }
  idx -= 2048;
  if (idx < 262144) { zb1[idx] = f2bf(z0[idx]); return; }
  idx -= 262144;
  if (idx < 524288) { h0b0[idx] = f2bf(h0in[idx]); return; }
  idx -= 524288;
  if (idx < 524288) { h1b0[idx] = f2bf(h0in[524288 + idx]); return; }
  idx -= 524288;
  if (idx < 32) { flags[idx] = 0; return; }  // [0..15] group flags, [16..23] xcd ctrs
}

// ---------------------------------------------------------------------------
// Group barrier: 16 same-XCD blocks, monotone counter. buffer_inv = per-CU
// vector-L1 invalidate only (L2 stays warm). Plain stores drained by the
// explicit vmcnt(0) + the s_barrier drain.
// ---------------------------------------------------------------------------
__device__ __forceinline__ void group_barrier(int* flag, int target) {
  asm volatile("s_waitcnt vmcnt(0)" ::: "memory");
  __syncthreads();
  if (threadIdx.x == 0) {
    __hip_atomic_fetch_add(flag, 1, __ATOMIC_RELAXED, __HIP_MEMORY_SCOPE_AGENT);
    while (__hip_atomic_load(flag, __ATOMIC_RELAXED, __HIP_MEMORY_SCOPE_AGENT) < target)
      __builtin_amdgcn_s_sleep(2);
    asm volatile("buffer_inv" ::: "memory");
  }
  __syncthreads();
}

// one K128 tile of MFMA: 8 x (A from LDS, B from bt — LDS or global)
__device__ __forceinline__ void mfma_k128(const short* at, const short* bt,
                                          f32x16& acc, int gq, int mh, int l,
                                          int ln, int kh) {
#pragma unroll
  for (int s = 0; s < 8; ++s) {
    bf16x8 a = *(const bf16x8*)&at[(mh * 32 + ln) * AT_STRIDE + (s * 2 + kh) * 8];
    bf16x8 b = *(const bf16x8*)&bt[((s * 4 + gq) * 64 + l) * 8];
    acc = mfma_bf16(a, b, acc);
  }
}

// ---------------------------------------------------------------------------
// LSTM cell phase: gates = [A|B panels] @ W^T + bias; c in regs; h -> plain
// store (same-XCD L2). First NLDS B-tiles come from LDS cache (wlds).
// ---------------------------------------------------------------------------
template <int NT, int TA, int NLDS>
__device__ __forceinline__ void cell_phase(
    short* At0, short* At1, float* gbuf,
    const short* __restrict__ srcA, int ldA,
    const short* __restrict__ srcB, int ldB,
    const short* wlds, const short* __restrict__ wglob,
    const float* __restrict__ bias,
    float* cr, short* hout, int row0, int j0)
{
  const int t = threadIdx.x;
  const int w = t >> 6, l = t & 63;
  const int gq = w >> 1, mh = w & 1;
  const int ln = l & 31, kh = l >> 5;
  const int sks = t & 15, sm = t >> 4;   // staging: ks 0..15, m 0..31 (+32)
  short* Abuf[2] = {At0, At1};
  f32x16 acc = zero16();
  uint4 pre[2];
#pragma unroll
  for (int i = 0; i < 2; ++i)
    pre[i] = *(const uint4*)&srcA[(row0 + sm + 32 * i) * ldA + sks * 8];
#pragma unroll
  for (int i = 0; i < 2; ++i)
    *(uint4*)&Abuf[0][(sm + 32 * i) * AT_STRIDE + sks * 8] = pre[i];
  __syncthreads();
#pragma unroll
  for (int tau = 0; tau < NT; ++tau) {
    if (tau + 1 < NT) {
      const short* src; int ld, col;
      if (tau + 1 < TA) { src = srcA; ld = ldA; col = (tau + 1) * 128; }
      else              { src = srcB; ld = ldB; col = (tau + 1 - TA) * 128; }
#pragma unroll
      for (int i = 0; i < 2; ++i)
        pre[i] = *(const uint4*)&src[(row0 + sm + 32 * i) * ld + col + sks * 8];
    }
    const short* at = Abuf[tau & 1];
    if (tau < NLDS) mfma_k128(at, wlds + tau * 16384, acc, gq, mh, l, ln, kh);
    else            mfma_k128(at, wglob + tau * 16384, acc, gq, mh, l, ln, kh);
    if (tau + 1 < NT) {
      short* nxt = Abuf[(tau + 1) & 1];
#pragma unroll
      for (int i = 0; i < 2; ++i)
        *(uint4*)&nxt[(sm + 32 * i) * AT_STRIDE + sks * 8] = pre[i];
    }
    __syncthreads();
  }
  // C layout: col = lane&31, row = (r&3)+8*(r>>2)+4*(lane>>5). gbuf aliases At.
#pragma unroll
  for (int r = 0; r < 16; ++r) {
    int mloc = (r & 3) + 8 * (r >> 2) + 4 * kh + mh * 32;
    gbuf[(gq * 64 + mloc) * 32 + ln] = acc[r];
  }
  __syncthreads();
  const int m = t >> 3, nb = (t & 7) * 4;
  short hh[4];
#pragma unroll
  for (int u = 0; u < 4; ++u) {
    int n = nb + u, jn = j0 + n;
    float gi = gbuf[(0 * 64 + m) * 32 + n] + bias[jn];
    float gf = gbuf[(1 * 64 + m) * 32 + n] + bias[512 + jn];
    float gg = gbuf[(2 * 64 + m) * 32 + n] + bias[1024 + jn];
    float go = gbuf[(3 * 64 + m) * 32 + n] + bias[1536 + jn];
    float cn = sigm(gf) * cr[u] + sigm(gi) * tanh_fast(gg);
    cr[u] = cn;
    hh[u] = f2bf(sigm(go) * tanh_fast(cn));
  }
  ull hv; __builtin_memcpy(&hv, hh, 8);
  *(ull*)&hout[(size_t)(row0 + m) * 512 + j0 + nb] = hv;  // plain: same-XCD L2
}

// ---------------------------------------------------------------------------
// Projection partials (fc or lin): B entirely from LDS cache. Waves
// (kq = w>>1, mh = w&1); 4 K-partials land in gbuf[kq][m][n] for combine.
// ---------------------------------------------------------------------------
template <int NQ>
__device__ __forceinline__ void proj_partials(
    short* At0, float* gbuf,
    const short* __restrict__ src, int ld,
    const short* wblk, int row0)
{
  const int t = threadIdx.x;
  const int w = t >> 6, l = t & 63;
  const int kq = w >> 1, mh = w & 1;
  const int ln = l & 31, kh = l >> 5;
  const int sks = t & 15, sm = t >> 4;
  f32x16 acc = zero16();
#pragma unroll
  for (int q = 0; q < NQ; ++q) {
    __syncthreads();
    uint4 pre[2];
#pragma unroll
    for (int i = 0; i < 2; ++i)
      pre[i] = *(const uint4*)&src[(row0 + sm + 32 * i) * ld + q * 128 + sks * 8];
#pragma unroll
    for (int i = 0; i < 2; ++i)
      *(uint4*)&At0[(sm + 32 * i) * AT_STRIDE + sks * 8] = pre[i];
    __syncthreads();
#pragma unroll
    for (int sl = 0; sl < 2; ++sl) {
      int s16 = kq * 2 + sl;
      bf16x8 a = *(const bf16x8*)&At0[(mh * 32 + ln) * AT_STRIDE + (s16 * 2 + kh) * 8];
      bf16x8 b = *(const bf16x8*)&wblk[((q * 8 + s16) * 64 + l) * 8];
      acc = mfma_bf16(a, b, acc);
    }
  }
  __syncthreads();
#pragma unroll
  for (int r = 0; r < 16; ++r) {
    int mloc = (r & 3) + 8 * (r >> 2) + 4 * kh + mh * 32;
    gbuf[(kq * 64 + mloc) * 32 + ln] = acc[r];
  }
  __syncthreads();
}

__global__ __launch_bounds__(512, 1) void decoder_persist(
    const short* __restrict__ wsw0, const short* __restrict__ wsw1,
    const short* __restrict__ fcWsw, const short* __restrict__ linWsw,
    const float* __restrict__ bias0, const float* __restrict__ bias1,
    const float* __restrict__ fcb, const float* __restrict__ linb,
    const float* __restrict__ c0in,
    short* h0x, short* h0y, short* h1x, short* h1y, short* zx, short* zy,
    int* flags, float* __restrict__ outp)
{
  __shared__ __align__(16) char arena[2 * AT_WORDS * 2];  // 33792 B (A dbuf / gbuf)
  __shared__ __align__(16) short wc[57344];               // 114688 B weight cache
  __shared__ int sgj[2];
  short* At0 = (short*)arena;
  short* At1 = At0 + AT_WORDS;
  float* gbuf = (float*)arena;   // 32768 B, aliases the A tiles

  // --- self-assignment: physical XCD id -> (group, j) slot ---
  if (threadIdx.x == 0) {
    unsigned xcc;
    asm volatile("s_getreg_b32 %0, hwreg(HW_REG_XCC_ID, 0, 32)" : "=s"(xcc));
    xcc &= 7u;
    int slot = __hip_atomic_fetch_add(&flags[16 + xcc], 1,
                                      __ATOMIC_RELAXED, __HIP_MEMORY_SCOPE_AGENT);
    sgj[0] = (int)xcc * 2 + (slot >> 4);  // group: 2 per XCD
    sgj[1] = slot & 15;                   // j-tile within group
  }
  __syncthreads();
  const int g = sgj[0], j = sgj[1];
  const int row0 = g * 64, j0 = j * 32;
  int* flag = &flags[g];

  // --- park fc/lin slice + leading cell1 B-tiles in LDS (loaded once) ---
  if (j < 8) {
    const short* s1 = fcWsw + j * 16384;
    for (int i = threadIdx.x; i < 2048; i += 512)
      *(uint4*)&wc[i * 8] = *(const uint4*)&s1[i * 8];
    const short* s2 = wsw1 + j * 131072;
    for (int i = threadIdx.x; i < 4096; i += 512)   // 2 tiles
      *(uint4*)&wc[16384 + i * 8] = *(const uint4*)&s2[i * 8];
  } else {
    const short* s1 = linWsw + (j - 8) * 8192;
    for (int i = threadIdx.x; i < 1024; i += 512)
      *(uint4*)&wc[i * 8] = *(const uint4*)&s1[i * 8];
    const short* s2 = wsw1 + j * 131072;
    for (int i = threadIdx.x; i < 6144; i += 512)   // 3 tiles
      *(uint4*)&wc[8192 + i * 8] = *(const uint4*)&s2[i * 8];
  }
  const short* wl1 = wc + (j < 8 ? 16384 : 8192);
  __syncthreads();

  // --- c-state in registers for the whole run ---
  float c0r[4], c1r[4];
  {
    const int m = threadIdx.x >> 3, nb = (threadIdx.x & 7) * 4;
#pragma unroll
    for (int u = 0; u < 4; ++u) {
      c0r[u] = c0in[(size_t)(row0 + m) * 512 + j0 + nb + u];
      c1r[u] = c0in[524288 + (size_t)(row0 + m) * 512 + j0 + nb + u];
    }
  }

  short* h0buf[2] = {h0x, h0y};
  short* h1buf[2] = {h1x, h1y};
  short* zbuf[2] = {zx, zy};
  const short* wg0 = wsw0 + j * 98304;
  const short* wg1 = wsw1 + j * 131072;

  int target = 0;
#pragma unroll 1
  for (int t = 0; t < 128; ++t) {
    const int p = t & 1;
    // P1: cell0  (K = [z 256 | h0 512])
    cell_phase<6, 2, 0>(At0, At1, gbuf, zbuf[p ^ 1], 256, h0buf[p], 512,
                        nullptr, wg0, bias0, c0r, h0buf[p ^ 1], row0, j0);
    target += 16; group_barrier(flag, target);
    // P2: cell1  (K = [h0_new 512 | h1 512]); first 2-3 B-tiles from LDS
    if (j < 8)
      cell_phase<8, 4, 2>(At0, At1, gbuf, h0buf[p ^ 1], 512, h1buf[p], 512,
                          wl1, wg1, bias1, c1r, h1buf[p ^ 1], row0, j0);
    else
      cell_phase<8, 4, 3>(At0, At1, gbuf, h0buf[p ^ 1], 512, h1buf[p], 512,
                          wl1, wg1, bias1, c1r, h1buf[p ^ 1], row0, j0);
    target += 16; group_barrier(flag, target);
    // P3: j<8 -> z(t) = fc(h1); j>=8 -> out(t-1) = lin(z(t-1))
    if (j < 8) {
      proj_partials<4>(At0, gbuf, h1buf[p ^ 1], 512, wc, row0);
      const int m = threadIdx.x >> 3, nb = (threadIdx.x & 7) * 4;
      const int n0 = j * 32;
      short zz[4];
#pragma unroll
      for (int u = 0; u < 4; ++u) {
        int n = nb + u;
        float v = gbuf[(0 * 64 + m) * 32 + n] + gbuf[(1 * 64 + m) * 32 + n] +
                  gbuf[(2 * 64 + m) * 32 + n] + gbuf[(3 * 64 + m) * 32 + n] +
                  fcb[n0 + n];
        zz[u] = f2bf(v);
      }
      ull zv; __builtin_memcpy(&zv, zz, 8);
      *(ull*)&zbuf[p][(size_t)(row0 + m) * 256 + n0 + nb] = zv;
    } else if (t > 0) {
      proj_partials<2>(At0, gbuf, zbuf[p ^ 1], 256, wc, row0);
      const int m = threadIdx.x >> 3, nb = (threadIdx.x & 7) * 4;
      const int n0 = (j - 8) * 32;
      float4 ov;
      float* po = &ov.x;
#pragma unroll
      for (int u = 0; u < 4; ++u) {
        int n = nb + u;
        po[u] = gbuf[(0 * 64 + m) * 32 + n] + gbuf[(1 * 64 + m) * 32 + n] +
                gbuf[(2 * 64 + m) * 32 + n] + gbuf[(3 * 64 + m) * 32 + n] +
                linb[n0 + n];
      }
      *(float4*)&outp[(size_t)(t - 1) * 262144 + (size_t)(row0 + m) * 256 + n0 + nb] = ov;
    }
    target += 16; group_barrier(flag, target);
  }
  // final out(127) from z(127) in zbuf[1]
  if (j >= 8) {
    proj_partials<2>(At0, gbuf, zbuf[1], 256, wc, row0);
    const int m = threadIdx.x >> 3, nb = (threadIdx.x & 7) * 4;
    const int n0 = (j - 8) * 32;
    float4 ov;
    float* po = &ov.x;
#pragma unroll
    for (int u = 0; u < 4; ++u) {
      int n = nb + u;
      po[u] = gbuf[(0 * 64 + m) * 32 + n] + gbuf[(1 * 64 + m) * 32 + n] +
              gbuf[(2 * 64 + m) * 32 + n] + gbuf[(3 * 64 + m) * 32 + n] +
              linb[n0 + n];
    }
    *(float4*)&outp[(size_t)127 * 262144 + (size_t)(row0 + m) * 256 + n0 + nb] = ov;
  }
}

// ---------------------------------------------------------------------------
extern "C" void kernel_launch(void* const* d_in, const int* in_sizes, int n_in,
                              void* d_out, int out_size, void* d_ws, size_t ws_size,
                              hipStream_t stream) {
  const float* z0   = (const float*)d_in[0];
  const float* h0in = (const float*)d_in[1];
  const float* c0in = (const float*)d_in[2];
  const float* Wih0 = (const float*)d_in[3];
  const float* Whh0 = (const float*)d_in[4];
  const float* bih0 = (const float*)d_in[5];
  const float* bhh0 = (const float*)d_in[6];
  const float* Wih1 = (const float*)d_in[7];
  const float* Whh1 = (const float*)d_in[8];
  const float* bih1 = (const float*)d_in[9];
  const float* bhh1 = (const float*)d_in[10];
  const float* fcW  = (const float*)d_in[11];
  const float* fcb  = (const float*)d_in[12];
  const float* linW = (const float*)d_in[13];
  const float* linb = (const float*)d_in[14];
  float* out = (float*)d_out;

  char* ws = (char*)d_ws;
  short* wsw0  = (short*)(ws + 0);         // 3,145,728 B
  short* wsw1  = (short*)(ws + 3145728);   // 4,194,304 B
  short* fcWsw = (short*)(ws + 7340032);   //   262,144 B
  short* linWsw= (short*)(ws + 7602176);   //   131,072 B
  float* bias0 = (float*)(ws + 7733248);   //     8,192 B
  float* bias1 = (float*)(ws + 7741440);   //     8,192 B
  short* zb0   = (short*)(ws + 7749632);   //   524,288 B
  short* zb1   = (short*)(ws + 8273920);   //   524,288 B
  short* h0b0  = (short*)(ws + 8798208);   // 1,048,576 B
  short* h0b1  = (short*)(ws + 9846784);
  short* h1b0  = (short*)(ws + 10895360);
  short* h1b1  = (short*)(ws + 11943936);
  int*   flags = (int*)  (ws + 12992512);  //       128 B (total ~13 MB)

  prep_kernel<<<20241, 256, 0, stream>>>(z0, h0in, Wih0, Whh0, bih0, bhh0,
                                         Wih1, Whh1, bih1, bhh1, fcW, linW,
                                         wsw0, wsw1, fcWsw, linWsw, bias0, bias1,
                                         zb1, h0b0, h1b0, flags);

  decoder_persist<<<256, 512, 0, stream>>>(
      wsw0, wsw1, fcWsw, linWsw, bias0, bias1, fcb, linb, c0in,
      h0b0, h0b1, h1b0, h1b1, zb0, zb1, flags, out);
}